// Round 5
// baseline (417.039 us; speedup 1.0000x reference)
//
#include <hip/hip_runtime.h>

// Integrator (scaling & squaring), vel [16,2,512,512] f32, with logdet-Jacobian.
// TWO integration steps fused per kernel: disp_{s+1} is pointwise-computable from
// disp_s, so corner values are recomputed in-kernel (cache hits) instead of a
// memory round-trip. 5 dispatches: init, 3x double-step, 1x final single step.
// Intermediates: disp interleaved [N,HW,2], ldjac plane [N,HW]. f32 throughout,
// bit-identical to the unfused sequence.
// Ping-pong: init->A(d_out scratch); DS: A->B, B->A, A->B; final: B->planar d_out.

#define NB 16
#define HH 512
#define WW 512
#define HW (HH * WW)          // 262144 = 1<<18
#define TOT (NB * HW)         // 4194304
#define EPS 0.0078125f        // 2^-7
#define DISP_ELEMS (NB * 2 * HW)   // 8388608 floats = 32 MiB
#define SC (512.0f / 511.0f)

typedef float f32x2 __attribute__((ext_vector_type(2)));
typedef float f32x4 __attribute__((ext_vector_type(4)));

struct Samp {
    int yc0, xc0, yc1, xc1;   // clamped corner coords
    float w00, w01, w10, w11; // bilinear weights, OOB folded to 0
};

__device__ __forceinline__ Samp make_samp(float sy, float sx) {
    float fy = floorf(sy), fx = floorf(sx);
    float wy = sy - fy, wx = sx - fx;
    int y0 = (int)fy, x0 = (int)fx;
    int y1 = y0 + 1, x1 = x0 + 1;
    bool xv0 = (unsigned)x0 < (unsigned)WW;
    bool xv1 = (unsigned)x1 < (unsigned)WW;
    bool yv0 = (unsigned)y0 < (unsigned)HH;
    bool yv1 = (unsigned)y1 < (unsigned)HH;
    Samp s;
    s.xc0 = min(max(x0, 0), WW - 1); s.xc1 = min(max(x1, 0), WW - 1);
    s.yc0 = min(max(y0, 0), HH - 1); s.yc1 = min(max(y1, 0), HH - 1);
    float omwx = 1.0f - wx, omwy = 1.0f - wy;
    s.w00 = (xv0 && yv0) ? omwx * omwy : 0.0f;
    s.w01 = (xv1 && yv0) ? wx * omwy   : 0.0f;
    s.w10 = (xv0 && yv1) ? omwx * wy   : 0.0f;
    s.w11 = (xv1 && yv1) ? wx * wy     : 0.0f;
    return s;
}

// one-step disp update evaluated at integer pixel (iy,ix) from interleaved plane dp
__device__ __forceinline__ f32x2 computeE(const float* __restrict__ dp, int iy, int ix) {
    f32x2 d = *(const f32x2*)(dp + 2 * (iy * WW + ix));
    float sy = ((float)iy + d.x) * SC - 0.5f;
    float sx = ((float)ix + d.y) * SC - 0.5f;
    Samp s = make_samp(sy, sx);
    f32x2 g00 = *(const f32x2*)(dp + 2 * (s.yc0 * WW + s.xc0));
    f32x2 g01 = *(const f32x2*)(dp + 2 * (s.yc0 * WW + s.xc1));
    f32x2 g10 = *(const f32x2*)(dp + 2 * (s.yc1 * WW + s.xc0));
    f32x2 g11 = *(const f32x2*)(dp + 2 * (s.yc1 * WW + s.xc1));
    f32x2 r;
    r.x = d.x + s.w00 * g00.x + s.w01 * g01.x + s.w10 * g10.x + s.w11 * g11.x;
    r.y = d.y + s.w00 * g00.y + s.w01 * g01.y + s.w10 * g10.y + s.w11 * g11.y;
    return r;
}

// one-step ldjac update at integer pixel (iy,ix): L'(q) = L(q) + bilerp(L, phi(q, E(q)))
__device__ __forceinline__ float computeLp(const float* __restrict__ dp,
                                           const float* __restrict__ lp, int iy, int ix) {
    f32x2 e = computeE(dp, iy, ix);
    float sy = ((float)iy + e.x) * SC - 0.5f;
    float sx = ((float)ix + e.y) * SC - 0.5f;
    Samp s = make_samp(sy, sx);
    return lp[iy * WW + ix]
         + s.w00 * lp[s.yc0 * WW + s.xc0] + s.w01 * lp[s.yc0 * WW + s.xc1]
         + s.w10 * lp[s.yc1 * WW + s.xc0] + s.w11 * lp[s.yc1 * WW + s.xc1];
}

__device__ __forceinline__ float logdet4(float a, float b, float c, float d) {
    float tr1 = a + d;
    float xa = a * a + b * c, xb = a * b + b * d;
    float xc = c * a + d * c, xd = c * b + d * d;
    float tr2 = xa + xd;
    float ya = xa * a + xb * c, yb = xa * b + xb * d;
    float yc = xc * a + xd * c, yd = xc * b + xd * d;
    float tr3 = ya + yd;
    float tr4 = ya * a + yb * c + yc * b + yd * d;
    return EPS * tr1 - 0.5f * (EPS * EPS) * tr2
         + (1.0f / 3.0f) * (EPS * EPS * EPS) * tr3
         - 0.25f * (EPS * EPS * EPS * EPS) * tr4;
}

// init: disp0 = eps*vel (interleaved), ldjac0 = logdet series of sobel jacobian. 2 px/thread.
__global__ void __launch_bounds__(256) init_kernel(const float* __restrict__ vel,
                                                   float* __restrict__ ddst,
                                                   float* __restrict__ ldst) {
    int tid = blockIdx.x * 256 + threadIdx.x;
    int pix = tid * 2;
    if (pix >= TOT) return;
    int n = pix >> 18;
    int rem = pix & (HW - 1);
    int y = rem >> 9, x = rem & (WW - 1);   // x even

    const float* v0 = vel + (size_t)n * 2 * HW;
    const float* v1 = v0 + HW;

    int r0 = max(y - 1, 0) * WW;
    int r1 = y * WW;
    int r2 = min(y + 1, HH - 1) * WW;
    int c0 = max(x - 1, 0), c1 = x, c2 = x + 1, c3 = min(x + 2, WW - 1);

    float A[3][4], B[3][4];
    int rows[3] = {r0, r1, r2};
    int cols[4] = {c0, c1, c2, c3};
#pragma unroll
    for (int r = 0; r < 3; ++r)
#pragma unroll
        for (int c = 0; c < 4; ++c) {
            A[r][c] = v0[rows[r] + cols[c]];
            B[r][c] = v1[rows[r] + cols[c]];
        }

    float a0 = 0.125f * ((A[2][0] + 2.0f * A[2][1] + A[2][2]) - (A[0][0] + 2.0f * A[0][1] + A[0][2]));
    float b0 = 0.125f * ((A[0][2] + 2.0f * A[1][2] + A[2][2]) - (A[0][0] + 2.0f * A[1][0] + A[2][0]));
    float c0j = 0.125f * ((B[2][0] + 2.0f * B[2][1] + B[2][2]) - (B[0][0] + 2.0f * B[0][1] + B[0][2]));
    float d0j = 0.125f * ((B[0][2] + 2.0f * B[1][2] + B[2][2]) - (B[0][0] + 2.0f * B[1][0] + B[2][0]));

    float a1 = 0.125f * ((A[2][1] + 2.0f * A[2][2] + A[2][3]) - (A[0][1] + 2.0f * A[0][2] + A[0][3]));
    float b1 = 0.125f * ((A[0][3] + 2.0f * A[1][3] + A[2][3]) - (A[0][1] + 2.0f * A[1][1] + A[2][1]));
    float c1j = 0.125f * ((B[2][1] + 2.0f * B[2][2] + B[2][3]) - (B[0][1] + 2.0f * B[0][2] + B[0][3]));
    float d1j = 0.125f * ((B[0][3] + 2.0f * B[1][3] + B[2][3]) - (B[0][1] + 2.0f * B[1][1] + B[2][1]));

    f32x4 dd;
    dd.x = EPS * A[1][1];  dd.y = EPS * B[1][1];
    dd.z = EPS * A[1][2];  dd.w = EPS * B[1][2];
    *(f32x4*)(ddst + 2 * ((size_t)n * HW + rem)) = dd;

    f32x2 ld;
    ld.x = logdet4(a0, b0, c0j, d0j);
    ld.y = logdet4(a1, b1, c1j, d1j);
    *(f32x2*)(ldst + (size_t)n * HW + rem) = ld;
}

// TWO fused composition steps, 1 px/thread.
__global__ void __launch_bounds__(256) dstep_kernel(const float* __restrict__ dsrc,
                                                    const float* __restrict__ lsrc,
                                                    float* __restrict__ ddst,
                                                    float* __restrict__ ldst) {
    int idx = blockIdx.x * 256 + threadIdx.x;
    int n = idx >> 18;
    int rem = idx & (HW - 1);
    int y = rem >> 9, x = rem & (WW - 1);

    const float* dp = dsrc + 2 * ((size_t)n * HW);
    const float* lp = lsrc + (size_t)n * HW;

    // step A at p
    f32x2 Ep = computeE(dp, y, x);

    // step B: F(p) = E(p) + bilerp(E, phi(p, E(p))), E at corners recomputed
    float sy2 = ((float)y + Ep.x) * SC - 0.5f;
    float sx2 = ((float)x + Ep.y) * SC - 0.5f;
    Samp s2 = make_samp(sy2, sx2);
    f32x2 E00 = computeE(dp, s2.yc0, s2.xc0);
    f32x2 E01 = computeE(dp, s2.yc0, s2.xc1);
    f32x2 E10 = computeE(dp, s2.yc1, s2.xc0);
    f32x2 E11 = computeE(dp, s2.yc1, s2.xc1);
    f32x2 Fp;
    Fp.x = Ep.x + s2.w00 * E00.x + s2.w01 * E01.x + s2.w10 * E10.x + s2.w11 * E11.x;
    Fp.y = Ep.y + s2.w00 * E00.y + s2.w01 * E01.y + s2.w10 * E10.y + s2.w11 * E11.y;

    // L'(p): same sample location as s2
    float Lp1 = lp[rem]
              + s2.w00 * lp[s2.yc0 * WW + s2.xc0] + s2.w01 * lp[s2.yc0 * WW + s2.xc1]
              + s2.w10 * lp[s2.yc1 * WW + s2.xc0] + s2.w11 * lp[s2.yc1 * WW + s2.xc1];

    // L''(p) = L'(p) + bilerp(L', phi(p, F(p))), L' at corners recomputed
    float sy3 = ((float)y + Fp.x) * SC - 0.5f;
    float sx3 = ((float)x + Fp.y) * SC - 0.5f;
    Samp s3 = make_samp(sy3, sx3);
    float L00 = computeLp(dp, lp, s3.yc0, s3.xc0);
    float L01 = computeLp(dp, lp, s3.yc0, s3.xc1);
    float L10 = computeLp(dp, lp, s3.yc1, s3.xc0);
    float L11 = computeLp(dp, lp, s3.yc1, s3.xc1);
    float Lp2 = Lp1 + s3.w00 * L00 + s3.w01 * L01 + s3.w10 * L10 + s3.w11 * L11;

    *(f32x2*)(ddst + 2 * ((size_t)n * HW + rem)) = Fp;
    ldst[(size_t)n * HW + rem] = Lp2;
}

// final single step: reads interleaved, writes planar disp + ldjac into d_out
__global__ void __launch_bounds__(256) final_kernel(const float* __restrict__ dsrc,
                                                    const float* __restrict__ lsrc,
                                                    float* __restrict__ dout,
                                                    float* __restrict__ lout) {
    int idx = blockIdx.x * 256 + threadIdx.x;
    int n = idx >> 18;
    int rem = idx & (HW - 1);
    int y = rem >> 9, x = rem & (WW - 1);

    const float* dp = dsrc + 2 * ((size_t)n * HW);
    const float* lp = lsrc + (size_t)n * HW;

    f32x2 Ep = computeE(dp, y, x);

    float sy2 = ((float)y + Ep.x) * SC - 0.5f;
    float sx2 = ((float)x + Ep.y) * SC - 0.5f;
    Samp s2 = make_samp(sy2, sx2);
    float Lp1 = lp[rem]
              + s2.w00 * lp[s2.yc0 * WW + s2.xc0] + s2.w01 * lp[s2.yc0 * WW + s2.xc1]
              + s2.w10 * lp[s2.yc1 * WW + s2.xc0] + s2.w11 * lp[s2.yc1 * WW + s2.xc1];

    float* pd = dout + (size_t)n * 2 * HW;
    pd[rem] = Ep.x;
    pd[HW + rem] = Ep.y;
    lout[(size_t)n * HW + rem] = Lp1;
}

extern "C" void kernel_launch(void* const* d_in, const int* in_sizes, int n_in,
                              void* d_out, int out_size, void* d_ws, size_t ws_size,
                              hipStream_t stream) {
    const float* vel = (const float*)d_in[0];
    float* out = (float*)d_out;
    float* ws = (float*)d_ws;

    float* dispA = out;                    // d_out as raw interleaved scratch until final
    float* ldjA  = out + DISP_ELEMS;
    float* dispB = ws;
    float* ldjB  = ws + DISP_ELEMS;

    dim3 block(256);
    dim3 grid_half(TOT / 2 / 256);   // init: 2 px/thread
    dim3 grid_full(TOT / 256);       // steps: 1 px/thread

    // init -> A ; DS(1-2): A->B ; DS(3-4): B->A ; DS(5-6): A->B ; final(7): B->planar d_out
    init_kernel<<<grid_half, block, 0, stream>>>(vel, dispA, ldjA);
    dstep_kernel<<<grid_full, block, 0, stream>>>(dispA, ldjA, dispB, ldjB);
    dstep_kernel<<<grid_full, block, 0, stream>>>(dispB, ldjB, dispA, ldjA);
    dstep_kernel<<<grid_full, block, 0, stream>>>(dispA, ldjA, dispB, ldjB);
    final_kernel<<<grid_full, block, 0, stream>>>(dispB, ldjB, out, out + DISP_ELEMS);
}

// Round 6
// 168.253 us; speedup vs baseline: 2.4786x; 2.4786x over previous
//
#include <hip/hip_runtime.h>

// Integrator (scaling & squaring) for vel [16,2,512,512] f32, with logdet-Jacobian.
// Layout: planar [N,C,H,W] f32 (round-1 structure, 1 px/thread).
// ONLY change vs the 210us baseline: XCD-aware block remap in step_kernel so
// XCD c owns images {2c,2c+1} with rows ascending -> bilinear gather targets
// stay in that XCD's 4MB L2 band; kills the ~2x duplicate HBM fetch seen in
// round-5 counters (FETCH 94.7MB for a 48MB src).
// Ping-pong: init -> ws ; steps alternate ws<->d_out ; 7th step lands in d_out.
// ws requirement: (8388608 + 4194304) * 4 = 48 MiB.

#define NB 16
#define HH 512
#define WW 512
#define HW (HH * WW)          // 262144 = 1<<18
#define TOT (NB * HW)         // 4194304
#define EPS 0.0078125f        // 2^-7
#define DISP_ELEMS (NB * 2 * HW)   // 8388608

struct Samp {
    int i00, i01, i10, i11;   // clamped plane offsets (y*W+x)
    float w00, w01, w10, w11; // bilinear weights with OOB folded to 0
};

__device__ __forceinline__ Samp make_samp(float sy, float sx) {
    float fy = floorf(sy), fx = floorf(sx);
    float wy = sy - fy, wx = sx - fx;
    int y0 = (int)fy, x0 = (int)fx;
    int y1 = y0 + 1, x1 = x0 + 1;
    bool xv0 = (unsigned)x0 < (unsigned)WW;
    bool xv1 = (unsigned)x1 < (unsigned)WW;
    bool yv0 = (unsigned)y0 < (unsigned)HH;
    bool yv1 = (unsigned)y1 < (unsigned)HH;
    int xc0 = min(max(x0, 0), WW - 1), xc1 = min(max(x1, 0), WW - 1);
    int yc0 = min(max(y0, 0), HH - 1), yc1 = min(max(y1, 0), HH - 1);
    Samp s;
    s.i00 = yc0 * WW + xc0; s.i01 = yc0 * WW + xc1;
    s.i10 = yc1 * WW + xc0; s.i11 = yc1 * WW + xc1;
    float omwx = 1.0f - wx, omwy = 1.0f - wy;
    s.w00 = (xv0 && yv0) ? omwx * omwy : 0.0f;
    s.w01 = (xv1 && yv0) ? wx * omwy   : 0.0f;
    s.w10 = (xv0 && yv1) ? omwx * wy   : 0.0f;
    s.w11 = (xv1 && yv1) ? wx * wy     : 0.0f;
    return s;
}

// init: disp0 = eps*vel ; ldjac0 = -sum_n (-eps)^n tr(J^n)/n  (J = sobel jacobian of vel)
__global__ void __launch_bounds__(256) init_kernel(const float* __restrict__ vel,
                                                   float* __restrict__ ddst,
                                                   float* __restrict__ ldst) {
    int idx = blockIdx.x * 256 + threadIdx.x;
    if (idx >= TOT) return;
    int n = idx >> 18;
    int rem = idx & (HW - 1);
    int y = rem >> 9, x = rem & (WW - 1);

    const float* v0 = vel + (size_t)n * 2 * HW;  // vel channel 0 (y-vel)
    const float* v1 = v0 + HW;                   // vel channel 1 (x-vel)

    float c0 = v0[rem], c1 = v1[rem];
    ddst[(size_t)n * 2 * HW + rem] = EPS * c0;
    ddst[(size_t)n * 2 * HW + HW + rem] = EPS * c1;

    int ym = max(y - 1, 0), yp = min(y + 1, HH - 1);
    int xm = max(x - 1, 0), xp = min(x + 1, WW - 1);
    int rmm = ym * WW + xm, rm0 = ym * WW + x, rmp = ym * WW + xp;
    int r0m = y * WW + xm,                    r0p = y * WW + xp;
    int rpm = yp * WW + xm, rp0 = yp * WW + x, rpp = yp * WW + xp;

    float a, b, c, d;
    {
        float tmm = v0[rmm], tm0 = v0[rm0], tmp = v0[rmp];
        float t0m = v0[r0m],                t0p = v0[r0p];
        float tpm = v0[rpm], tp0 = v0[rp0], tpp = v0[rpp];
        a = 0.125f * ((tpm + 2.0f * tp0 + tpp) - (tmm + 2.0f * tm0 + tmp)); // d vel_y / dy
        b = 0.125f * ((tmp + 2.0f * t0p + tpp) - (tmm + 2.0f * t0m + tpm)); // d vel_y / dx
    }
    {
        float tmm = v1[rmm], tm0 = v1[rm0], tmp = v1[rmp];
        float t0m = v1[r0m],                t0p = v1[r0p];
        float tpm = v1[rpm], tp0 = v1[rp0], tpp = v1[rpp];
        c = 0.125f * ((tpm + 2.0f * tp0 + tpp) - (tmm + 2.0f * tm0 + tmp)); // d vel_x / dy
        d = 0.125f * ((tmp + 2.0f * t0p + tpp) - (tmm + 2.0f * t0m + tpm)); // d vel_x / dx
    }

    float xa = a, xb = b, xc = c, xd = d;
    float ld = EPS * (xa + xd);
    float na = xa * a + xb * c, nb = xa * b + xb * d;
    float nc = xc * a + xd * c, nd = xc * b + xd * d;
    xa = na; xb = nb; xc = nc; xd = nd;
    ld -= (EPS * EPS) * (xa + xd) * 0.5f;
    na = xa * a + xb * c; nb = xa * b + xb * d;
    nc = xc * a + xd * c; nd = xc * b + xd * d;
    xa = na; xb = nb; xc = nc; xd = nd;
    ld += (EPS * EPS * EPS) * (xa + xd) * (1.0f / 3.0f);
    na = xa * a + xb * c;
    nd = xc * b + xd * d;
    ld -= (EPS * EPS * EPS * EPS) * (na + nd) * 0.25f;

    ldst[(size_t)n * HW + rem] = ld;
}

// one composition step, fused disp + ldjac update, XCD-remapped tasks:
//   disp_new(p)  = disp(p)  + bilerp(disp,  p + disp(p))
//   ldjac_new(p) = ldjac(p) + bilerp(ldjac, p + disp_new(p))
__global__ void __launch_bounds__(256) step_kernel(const float* __restrict__ dsrc,
                                                   const float* __restrict__ lsrc,
                                                   float* __restrict__ ddst,
                                                   float* __restrict__ ldst) {
    // 16384 half-row tasks; XCD c (= bid&7 under round-robin dispatch) gets
    // tasks [c*2048,(c+1)*2048) = images {2c,2c+1}, rows ascending.
    int bid = blockIdx.x;
    int task = ((bid & 7) << 11) | (bid >> 3);
    int idx = task * 256 + threadIdx.x;
    int n = idx >> 18;
    int rem = idx & (HW - 1);
    int y = rem >> 9, x = rem & (WW - 1);

    const float SC = 512.0f / 511.0f;

    const float* dy_p = dsrc + (size_t)n * 2 * HW;
    const float* dx_p = dy_p + HW;
    float d0 = dy_p[rem], d1 = dx_p[rem];

    float sy = ((float)y + d0) * SC - 0.5f;
    float sx = ((float)x + d1) * SC - 0.5f;
    Samp s = make_samp(sy, sx);

    float nd0 = d0 + s.w00 * dy_p[s.i00] + s.w01 * dy_p[s.i01]
                   + s.w10 * dy_p[s.i10] + s.w11 * dy_p[s.i11];
    float nd1 = d1 + s.w00 * dx_p[s.i00] + s.w01 * dx_p[s.i01]
                   + s.w10 * dx_p[s.i10] + s.w11 * dx_p[s.i11];

    ddst[(size_t)n * 2 * HW + rem] = nd0;
    ddst[(size_t)n * 2 * HW + HW + rem] = nd1;

    float sy2 = ((float)y + nd0) * SC - 0.5f;
    float sx2 = ((float)x + nd1) * SC - 0.5f;
    Samp s2 = make_samp(sy2, sx2);

    const float* l_p = lsrc + (size_t)n * HW;
    float l = l_p[rem];
    float nl = l + s2.w00 * l_p[s2.i00] + s2.w01 * l_p[s2.i01]
                 + s2.w10 * l_p[s2.i10] + s2.w11 * l_p[s2.i11];
    ldst[(size_t)n * HW + rem] = nl;
}

extern "C" void kernel_launch(void* const* d_in, const int* in_sizes, int n_in,
                              void* d_out, int out_size, void* d_ws, size_t ws_size,
                              hipStream_t stream) {
    const float* vel = (const float*)d_in[0];
    float* out = (float*)d_out;
    float* ws = (float*)d_ws;

    float* dispA = out;                    // d_out: disp (8388608 f32)
    float* ldjA  = out + DISP_ELEMS;       //        ldjac (4194304 f32)
    float* dispB = ws;                     // ws:   disp
    float* ldjB  = ws + DISP_ELEMS;        //       ldjac   (needs 48 MiB total)

    dim3 grid(TOT / 256), block(256);      // 16384 blocks

    // init into B (ws); 7 steps alternate: s=0 -> A(d_out), s=1 -> B, ... s=6 -> A(d_out)
    init_kernel<<<grid, block, 0, stream>>>(vel, dispB, ldjB);

    const float* ds = dispB;
    const float* ls = ldjB;
    for (int s = 0; s < 7; ++s) {
        float* dd  = (s & 1) ? dispB : dispA;
        float* ldd = (s & 1) ? ldjB  : ldjA;
        step_kernel<<<grid, block, 0, stream>>>(ds, ls, dd, ldd);
        ds = dd; ls = ldd;
    }
}

// Round 7
// 143.900 us; speedup vs baseline: 2.8981x; 1.1692x over previous
//
#include <hip/hip_runtime.h>

// Integrator (scaling & squaring) for vel [16,2,512,512] f32, with logdet-Jacobian.
// Round-6 structure (1 px/thread, XCD remap in steps, ping-pong) with FP16
// intermediates: disp interleaved [N,HW,2] as half2 (4B/px), ldjac [N,HW] as
// half (2B/px). Halves per-step HBM traffic 96MB -> 48MB. Final step reads
// fp16 and writes the required planar f32 output.
// Scratch sets: A = d_out raw bytes (24MB of 48MB), B = ws (24MB).

#define NB 16
#define HH 512
#define WW 512
#define HW (HH * WW)          // 262144 = 1<<18
#define TOT (NB * HW)         // 4194304
#define EPS 0.0078125f        // 2^-7
#define DISP_ELEMS (NB * 2 * HW)   // 8388608 (f32 elems of final planar disp)

typedef _Float16 f16;
typedef _Float16 f16x2 __attribute__((ext_vector_type(2)));

struct Samp {
    int i00, i01, i10, i11;   // clamped plane offsets (y*W+x)
    float w00, w01, w10, w11; // bilinear weights with OOB folded to 0
};

__device__ __forceinline__ Samp make_samp(float sy, float sx) {
    float fy = floorf(sy), fx = floorf(sx);
    float wy = sy - fy, wx = sx - fx;
    int y0 = (int)fy, x0 = (int)fx;
    int y1 = y0 + 1, x1 = x0 + 1;
    bool xv0 = (unsigned)x0 < (unsigned)WW;
    bool xv1 = (unsigned)x1 < (unsigned)WW;
    bool yv0 = (unsigned)y0 < (unsigned)HH;
    bool yv1 = (unsigned)y1 < (unsigned)HH;
    int xc0 = min(max(x0, 0), WW - 1), xc1 = min(max(x1, 0), WW - 1);
    int yc0 = min(max(y0, 0), HH - 1), yc1 = min(max(y1, 0), HH - 1);
    Samp s;
    s.i00 = yc0 * WW + xc0; s.i01 = yc0 * WW + xc1;
    s.i10 = yc1 * WW + xc0; s.i11 = yc1 * WW + xc1;
    float omwx = 1.0f - wx, omwy = 1.0f - wy;
    s.w00 = (xv0 && yv0) ? omwx * omwy : 0.0f;
    s.w01 = (xv1 && yv0) ? wx * omwy   : 0.0f;
    s.w10 = (xv0 && yv1) ? omwx * wy   : 0.0f;
    s.w11 = (xv1 && yv1) ? wx * wy     : 0.0f;
    return s;
}

// init: disp0 = eps*vel (fp16 interleaved) ; ldjac0 = logdet series (fp16)
__global__ void __launch_bounds__(256) init_kernel(const float* __restrict__ vel,
                                                   f16x2* __restrict__ ddst,
                                                   f16* __restrict__ ldst) {
    int idx = blockIdx.x * 256 + threadIdx.x;
    int n = idx >> 18;
    int rem = idx & (HW - 1);
    int y = rem >> 9, x = rem & (WW - 1);

    const float* v0 = vel + (size_t)n * 2 * HW;  // vel_y
    const float* v1 = v0 + HW;                   // vel_x

    float c0 = v0[rem], c1 = v1[rem];
    f16x2 dd; dd.x = (f16)(EPS * c0); dd.y = (f16)(EPS * c1);
    ddst[(size_t)n * HW + rem] = dd;

    int ym = max(y - 1, 0), yp = min(y + 1, HH - 1);
    int xm = max(x - 1, 0), xp = min(x + 1, WW - 1);
    int rmm = ym * WW + xm, rm0 = ym * WW + x, rmp = ym * WW + xp;
    int r0m = y * WW + xm,                    r0p = y * WW + xp;
    int rpm = yp * WW + xm, rp0 = yp * WW + x, rpp = yp * WW + xp;

    float a, b, c, d;
    {
        float tmm = v0[rmm], tm0 = v0[rm0], tmp = v0[rmp];
        float t0m = v0[r0m],                t0p = v0[r0p];
        float tpm = v0[rpm], tp0 = v0[rp0], tpp = v0[rpp];
        a = 0.125f * ((tpm + 2.0f * tp0 + tpp) - (tmm + 2.0f * tm0 + tmp));
        b = 0.125f * ((tmp + 2.0f * t0p + tpp) - (tmm + 2.0f * t0m + tpm));
    }
    {
        float tmm = v1[rmm], tm0 = v1[rm0], tmp = v1[rmp];
        float t0m = v1[r0m],                t0p = v1[r0p];
        float tpm = v1[rpm], tp0 = v1[rp0], tpp = v1[rpp];
        c = 0.125f * ((tpm + 2.0f * tp0 + tpp) - (tmm + 2.0f * tm0 + tmp));
        d = 0.125f * ((tmp + 2.0f * t0p + tpp) - (tmm + 2.0f * t0m + tpm));
    }

    float xa = a, xb = b, xc = c, xd = d;
    float ld = EPS * (xa + xd);
    float na = xa * a + xb * c, nb = xa * b + xb * d;
    float nc = xc * a + xd * c, nd = xc * b + xd * d;
    xa = na; xb = nb; xc = nc; xd = nd;
    ld -= (EPS * EPS) * (xa + xd) * 0.5f;
    na = xa * a + xb * c; nb = xa * b + xb * d;
    nc = xc * a + xd * c; nd = xc * b + xd * d;
    xa = na; xb = nb; xc = nc; xd = nd;
    ld += (EPS * EPS * EPS) * (xa + xd) * (1.0f / 3.0f);
    na = xa * a + xb * c;
    nd = xc * b + xd * d;
    ld -= (EPS * EPS * EPS * EPS) * (na + nd) * 0.25f;

    ldst[(size_t)n * HW + rem] = (f16)ld;
}

// one composition step (fp16 in; fp16 out normally, planar f32 out when FINAL),
// XCD-remapped tasks, fused disp + ldjac update.
template <bool FINAL>
__global__ void __launch_bounds__(256) step_kernel(const f16x2* __restrict__ dsrc,
                                                   const f16* __restrict__ lsrc,
                                                   f16x2* __restrict__ ddst,
                                                   f16* __restrict__ ldst,
                                                   float* __restrict__ doutp,
                                                   float* __restrict__ loutp) {
    // 16384 half-row tasks; XCD c (= bid&7) owns images {2c,2c+1}, rows ascending.
    int bid = blockIdx.x;
    int task = ((bid & 7) << 11) | (bid >> 3);
    int idx = task * 256 + threadIdx.x;
    int n = idx >> 18;
    int rem = idx & (HW - 1);
    int y = rem >> 9, x = rem & (WW - 1);

    const float SC = 512.0f / 511.0f;

    const f16x2* dp = dsrc + (size_t)n * HW;
    f16x2 dv = dp[rem];
    float d0 = (float)dv.x, d1 = (float)dv.y;

    float sy = ((float)y + d0) * SC - 0.5f;
    float sx = ((float)x + d1) * SC - 0.5f;
    Samp s = make_samp(sy, sx);

    f16x2 g00 = dp[s.i00], g01 = dp[s.i01], g10 = dp[s.i10], g11 = dp[s.i11];
    float nd0 = d0 + s.w00 * (float)g00.x + s.w01 * (float)g01.x
                   + s.w10 * (float)g10.x + s.w11 * (float)g11.x;
    float nd1 = d1 + s.w00 * (float)g00.y + s.w01 * (float)g01.y
                   + s.w10 * (float)g10.y + s.w11 * (float)g11.y;

    if (FINAL) {
        float* pd = doutp + (size_t)n * 2 * HW;
        pd[rem] = nd0;
        pd[HW + rem] = nd1;
    } else {
        f16x2 w; w.x = (f16)nd0; w.y = (f16)nd1;
        ddst[(size_t)n * HW + rem] = w;
    }

    // ldjac sampled with the NEW disp at this pixel
    float sy2 = ((float)y + nd0) * SC - 0.5f;
    float sx2 = ((float)x + nd1) * SC - 0.5f;
    Samp s2 = make_samp(sy2, sx2);

    const f16* lp = lsrc + (size_t)n * HW;
    float l = (float)lp[rem];
    float nl = l + s2.w00 * (float)lp[s2.i00] + s2.w01 * (float)lp[s2.i01]
                 + s2.w10 * (float)lp[s2.i10] + s2.w11 * (float)lp[s2.i11];
    if (FINAL) {
        loutp[(size_t)n * HW + rem] = nl;
    } else {
        ldst[(size_t)n * HW + rem] = (f16)nl;
    }
}

extern "C" void kernel_launch(void* const* d_in, const int* in_sizes, int n_in,
                              void* d_out, int out_size, void* d_ws, size_t ws_size,
                              hipStream_t stream) {
    const float* vel = (const float*)d_in[0];
    float* out = (float*)d_out;

    // fp16 scratch set A lives in d_out's raw bytes (24MB of 48MB), set B in ws.
    f16*   baseA = (f16*)d_out;
    f16*   baseB = (f16*)d_ws;
    f16x2* dA = (f16x2*)baseA;            // 8388608 halfs = 16MB
    f16*   lA = baseA + (size_t)2 * TOT;  // 4194304 halfs = 8MB
    f16x2* dB = (f16x2*)baseB;
    f16*   lB = baseB + (size_t)2 * TOT;

    dim3 grid(TOT / 256), block(256);     // 16384 blocks

    // init -> B ; s0:B->A s1:A->B s2:B->A s3:A->B s4:B->A s5:A->B ; final:B->f32 d_out
    init_kernel<<<grid, block, 0, stream>>>(vel, dB, lB);

    const f16x2* ds = dB;
    const f16*   ls = lB;
    for (int s = 0; s < 6; ++s) {
        f16x2* dd  = (s & 1) ? dB : dA;
        f16*   ldd = (s & 1) ? lB : lA;
        step_kernel<false><<<grid, block, 0, stream>>>(ds, ls, dd, ldd, nullptr, nullptr);
        ds = dd; ls = ldd;
    }
    step_kernel<true><<<grid, block, 0, stream>>>(ds, ls, nullptr, nullptr,
                                                  out, out + DISP_ELEMS);
}